// Round 15
// baseline (175.007 us; speedup 1.0000x reference)
//
#include <hip/hip_runtime.h>
#include <hip/hip_bf16.h>

// ---------------------------------------------------------------------------
// CompressedGlobalAttention: B=2, S=8192, D=1024, H=16, Hd=64, R=8,
// local_window_start=4096 -> P=512 pools.
//   1. prep kernel: fused {cast+compress} and {weight transpose}
//   2. Q via 8-phase 256^2 GEMM with epilogue PRESCALE by 0.125*log2(e);
//      K/V via fused dual GEMM, retiled 128x64 (grid 256 = all CUs; old
//      128x128 grid-128 left half the chip idle for its ~10us)
//   3. attention per (b,h): r14 structure. Fixed-base softmax P = exp2(s)
//      (Q prescaled), l via ones-MFMA (lac[0] = full row sum). First
//      slice's Q fragments loaded BEFORE __syncthreads so the HBM fetch
//      hides under K/V staging.
//   4. out via 8-phase 256^2 GEMM (oscale=1, f32 out)
// Dead-ends (measured): 1024-thr blocks (64-VGPR cliff r2/r8), (512,1)
// doesn't lift 128 cap (r12), global-K (r5), global-V (r6), LDS-halving
// (r9), 4-q-group widening (r12), cvt_pk alone (r10), balance/setprio (r11).
// GEMM structural levers (B-from-global, 32x32 MFMA, 128^2+8ph) rejected by
// register/vmcnt/measured-quadrant analysis - template ~732 TF at K=1024 is
// within ~15% of the m248 reference for this K.
// ---------------------------------------------------------------------------

typedef __attribute__((ext_vector_type(8))) short bf16x8;
typedef __attribute__((ext_vector_type(4))) short bf16x4;
typedef __attribute__((ext_vector_type(4))) float f32x4;

#define MFMA_BF16(a, b, c) __builtin_amdgcn_mfma_f32_16x16x32_bf16((a), (b), (c), 0, 0, 0)

__device__ __forceinline__ unsigned short f2bu(float x) {
  __hip_bfloat16 b = __float2bfloat16(x);
  return __builtin_bit_cast(unsigned short, b);
}

__device__ __forceinline__ unsigned cvtpk(float lo, float hi) {
  unsigned r;
  asm("v_cvt_pk_bf16_f32 %0, %1, %2" : "=v"(r) : "v"(lo), "v"(hi));
  return r;
}

__device__ __forceinline__ float fexp2(float x) {
  float r;
  asm("v_exp_f32 %0, %1" : "=v"(r) : "v"(x));
  return r;
}

__device__ __forceinline__ void gload_lds16(const void* g, void* l) {
  __builtin_amdgcn_global_load_lds(
      (const __attribute__((address_space(1))) unsigned*)(g),
      (__attribute__((address_space(3))) unsigned*)(l), 16, 0, 0);
}

__device__ __forceinline__ unsigned ldsaddr(const void* p) {
  return (unsigned)(unsigned long long)(const __attribute__((address_space(3))) char*)p;
}

// ---------------------------------------------------------------------------
// prep: blocks [0,2048) = cast x->bf16 + avg-pool compress;
//       blocks [2048,6144) = transpose 1024x1024 f32 weight -> bf16 Bt
__global__ void prep_kernel(const float* __restrict__ x,
                            __hip_bfloat16* __restrict__ xb,
                            __hip_bfloat16* __restrict__ cb,
                            const float* __restrict__ w0, const float* __restrict__ w1,
                            const float* __restrict__ w2, const float* __restrict__ w3,
                            __hip_bfloat16* __restrict__ t0, __hip_bfloat16* __restrict__ t1,
                            __hip_bfloat16* __restrict__ t2, __hip_bfloat16* __restrict__ t3) {
  __shared__ float tile[32][33];
  const int bid = blockIdx.x;
  const int tid = threadIdx.x;
  if (bid < 2048) {
    const int b = bid >> 10, g = bid & 1023;
    const int d = tid * 4;
    const size_t rb = ((size_t)(b * 8192 + g * 8)) * 1024 + d;
    float4 a = {0.f, 0.f, 0.f, 0.f};
#pragma unroll
    for (int r = 0; r < 8; ++r) {
      const float4 v = *(const float4*)&x[rb + (size_t)r * 1024];
      ushort4 o;
      o.x = f2bu(v.x); o.y = f2bu(v.y); o.z = f2bu(v.z); o.w = f2bu(v.w);
      *(ushort4*)&xb[rb + (size_t)r * 1024] = o;
      a.x += v.x; a.y += v.y; a.z += v.z; a.w += v.w;
    }
    if (g < 512) {
      ushort4 o;
      o.x = f2bu(a.x * 0.125f); o.y = f2bu(a.y * 0.125f);
      o.z = f2bu(a.z * 0.125f); o.w = f2bu(a.w * 0.125f);
      *(ushort4*)&cb[((size_t)(b * 512 + g)) * 1024 + d] = o;
    }
  } else {
    const int t = bid - 2048;
    const int z = t >> 10, rem = t & 1023;
    const int k0 = (rem & 31) * 32, n0 = (rem >> 5) * 32;
    const float* W; __hip_bfloat16* T;
    switch (z) {
      case 0: W = w0; T = t0; break;
      case 1: W = w1; T = t1; break;
      case 2: W = w2; T = t2; break;
      default: W = w3; T = t3; break;
    }
    const int tx = tid & 31, ty = tid >> 5;          // 32 x 8
#pragma unroll
    for (int j = 0; j < 4; ++j) {
      const int kk = ty + j * 8;
      tile[kk][tx] = W[(size_t)(k0 + kk) * 1024 + n0 + tx];
    }
    __syncthreads();
#pragma unroll
    for (int j = 0; j < 4; ++j) {
      const int nn = ty + j * 8;
      T[(size_t)(n0 + nn) * 1024 + k0 + tx] = __float2bfloat16(tile[tx][nn]);
    }
  }
}

// ---------------------------------------------------------------------------
// 8-phase 256x256xBK=64 GEMM (T2 swizzle + T3/T4 counted vmcnt + T5 setprio).
// Epilogue: C = (acc + bias) * oscale.
// ---------------------------------------------------------------------------

#define STAGE(SPTR, SROWBASE, STILE, SLDSOFF)                                  \
  {                                                                            \
    const int _t = (STILE) < NT ? (STILE) : 0;                                 \
    const size_t _kb = (size_t)_t * 128;                                       \
    gload_lds16((const char*)(SPTR) + ((size_t)((SROWBASE) + srow0) * K) * 2 + _kb + scb0, \
                ldsC + (SLDSOFF) + wave * 1024);                               \
    gload_lds16((const char*)(SPTR) + ((size_t)((SROWBASE) + srow0 + 64) * K) * 2 + _kb + scb0, \
                ldsC + (SLDSOFF) + 8192 + wave * 1024);                        \
  }

#define MM4(MR, AF0, AF1)                                                      \
  acc[MR][0] = MFMA_BF16(AF0, bf00, acc[MR][0]);                               \
  acc[MR][1] = MFMA_BF16(AF0, bf10, acc[MR][1]);                               \
  acc[MR][2] = MFMA_BF16(AF0, bf20, acc[MR][2]);                               \
  acc[MR][3] = MFMA_BF16(AF0, bf30, acc[MR][3]);                               \
  acc[MR][0] = MFMA_BF16(AF1, bf01, acc[MR][0]);                               \
  acc[MR][1] = MFMA_BF16(AF1, bf11, acc[MR][1]);                               \
  acc[MR][2] = MFMA_BF16(AF1, bf21, acc[MR][2]);                               \
  acc[MR][3] = MFMA_BF16(AF1, bf31, acc[MR][3]);

#define PHASE(QM, DB, LOADB, SPTR, SROWBASE, STILE, SLDSOFF, DOVM)             \
  {                                                                            \
    bf16x8 af0, af1, af2, af3;                                                 \
    const unsigned ab = Ab0 + (DB)*32768u + (QM)*4096u;                        \
    asm volatile("ds_read_b128 %0, %1" : "=v"(af0) : "v"(ab));                 \
    asm volatile("ds_read_b128 %0, %1" : "=v"(af1) : "v"(ab ^ 64u));           \
    asm volatile("ds_read_b128 %0, %1" : "=v"(af2) : "v"(ab + 2048u));         \
    asm volatile("ds_read_b128 %0, %1" : "=v"(af3) : "v"((ab + 2048u) ^ 64u)); \
    if (LOADB) {                                                               \
      const unsigned bb = Bb0 + (DB)*32768u;                                   \
      asm volatile("ds_read_b128 %0, %1" : "=v"(bf00) : "v"(bb));              \
      asm volatile("ds_read_b128 %0, %1" : "=v"(bf01) : "v"(bb ^ 64u));        \
      asm volatile("ds_read_b128 %0, %1" : "=v"(bf10) : "v"(bb + 2048u));      \
      asm volatile("ds_read_b128 %0, %1" : "=v"(bf11) : "v"((bb + 2048u) ^ 64u)); \
      asm volatile("ds_read_b128 %0, %1" : "=v"(bf20) : "v"(bb + 4096u));      \
      asm volatile("ds_read_b128 %0, %1" : "=v"(bf21) : "v"((bb + 4096u) ^ 64u)); \
      asm volatile("ds_read_b128 %0, %1" : "=v"(bf30) : "v"(bb + 6144u));      \
      asm volatile("ds_read_b128 %0, %1" : "=v"(bf31) : "v"((bb + 6144u) ^ 64u)); \
    }                                                                          \
    STAGE(SPTR, SROWBASE, STILE, SLDSOFF)                                      \
    asm volatile("s_barrier" ::: "memory");                                    \
    asm volatile("s_waitcnt lgkmcnt(0)" ::: "memory");                         \
    __builtin_amdgcn_sched_barrier(0);                                         \
    __builtin_amdgcn_s_setprio(1);                                             \
    MM4((QM)*2 + 0, af0, af1)                                                  \
    MM4((QM)*2 + 1, af2, af3)                                                  \
    __builtin_amdgcn_s_setprio(0);                                             \
    if (DOVM) asm volatile("s_waitcnt vmcnt(4)" ::: "memory");                 \
    asm volatile("s_barrier" ::: "memory");                                    \
  }

template <typename OUT_T>
__global__ __launch_bounds__(512, 2) void gemm256_kernel(
    const __hip_bfloat16* __restrict__ A, const __hip_bfloat16* __restrict__ Bt,
    const float* __restrict__ bias, OUT_T* __restrict__ C, int M, int N, int K,
    float oscale) {
  __shared__ alignas(16) char lds[131072];
  char* ldsC = lds;
  const int tid = threadIdx.x;
  const int wave = tid >> 6, lane = tid & 63;
  const int l15 = lane & 15, lg = lane >> 4;
  const int wm = wave >> 2, wn = wave & 3;

  const int nwg = gridDim.x, cpx = nwg >> 3;
  const int bid = blockIdx.x;
  const int swz = (bid & 7) * cpx + (bid >> 3);
  const int ncol = N >> 8;
  const int bn = swz % ncol, bm = swz / ncol;
  const long brow = (long)bm * 256;
  const long bcol = (long)bn * 256;

  const int NT = K >> 6;
  const int NITER = K >> 7;

  const int o0 = wave * 1024 + lane * 16;
  const int srow0 = o0 >> 7;
  const int scb0 = (o0 & 127) ^ ((srow0 & 7) << 4);

  const unsigned LB = ldsaddr(lds);
  const int off0 = (lg * 16) ^ ((l15 & 7) << 4);
  const unsigned Ab0 = LB + wm * 16384u + l15 * 128u + off0;
  const unsigned Bb0 = LB + 65536u + (wn >> 1) * 16384u + (wn & 1) * 8192u + l15 * 128u + off0;

  f32x4 acc[8][4];
#pragma unroll
  for (int m = 0; m < 8; ++m)
#pragma unroll
    for (int n = 0; n < 4; ++n) acc[m][n] = (f32x4){0.f, 0.f, 0.f, 0.f};

  bf16x8 bf00, bf01, bf10, bf11, bf20, bf21, bf30, bf31;

  STAGE(Bt, bcol + 128, 0, 81920)
  STAGE(Bt, bcol,       0, 65536)
  STAGE(A,  brow,       0, 0)
  STAGE(A,  brow + 128, 0, 16384)
  STAGE(Bt, bcol + 128, 1, 114688)
  STAGE(Bt, bcol,       1, 98304)
  asm volatile("s_waitcnt vmcnt(4)" ::: "memory");
  asm volatile("s_barrier" ::: "memory");

  for (int i = 0; i < NITER; ++i) {
    const int t0 = 2 * i;
    PHASE(0, 0, true,  A,  brow,       t0 + 1, 32768,  false)
    PHASE(1, 0, false, A,  brow + 128, t0 + 1, 49152,  false)
    PHASE(2, 0, false, Bt, bcol + 128, t0 + 2, 81920,  false)
    PHASE(3, 0, false, Bt, bcol,       t0 + 2, 65536,  true)
    PHASE(0, 1, true,  A,  brow,       t0 + 2, 0,      false)
    PHASE(1, 1, false, A,  brow + 128, t0 + 2, 16384,  false)
    PHASE(2, 1, false, Bt, bcol + 128, t0 + 3, 114688, false)
    PHASE(3, 1, false, Bt, bcol,       t0 + 3, 98304,  true)
  }

#pragma unroll
  for (int nn = 0; nn < 4; ++nn) {
    const long col = bcol + wn * 64 + nn * 16 + l15;
    const float bv = bias[col];
#pragma unroll
    for (int mr = 0; mr < 8; ++mr) {
      const long row = brow + wm * 128 + mr * 16 + lg * 4;
#pragma unroll
      for (int j = 0; j < 4; ++j) {
        const float v = (acc[mr][nn][j] + bv) * oscale;
        if constexpr (sizeof(OUT_T) == 2)
          C[(row + j) * N + col] = __float2bfloat16(v);
        else
          C[(row + j) * N + col] = v;
      }
    }
  }
}

// ---------------------------------------------------------------------------
// dual K/V projection GEMM, retiled 128x64 so grid = 256 (all CUs busy).
// grid (32, 8): x<16 -> K-proj col-tile x; x>=16 -> V-proj col-tile x-16.
// K written normally; V written TRANSPOSED: Vt[(b*1024 + h*64 + d)*512 + p]
__global__ __launch_bounds__(256, 2) void gemm_bt_dual_kernel(
    const __hip_bfloat16* __restrict__ A,
    const __hip_bfloat16* __restrict__ Bt0, const float* __restrict__ b0,
    __hip_bfloat16* __restrict__ C0,
    const __hip_bfloat16* __restrict__ Bt1, const float* __restrict__ b1,
    __hip_bfloat16* __restrict__ Vt, int M, int N, int K) {
  const int sel = blockIdx.x >= 16;
  const __hip_bfloat16* Bt = sel ? Bt1 : Bt0;
  const float* bias = sel ? b1 : b0;
  const int bx = blockIdx.x - (sel ? 16 : 0);

  __shared__ alignas(16) __hip_bfloat16 As[128 * 32];
  __shared__ alignas(16) __hip_bfloat16 Bs[64 * 32];
  const int tid = threadIdx.x;
  const int wave = tid >> 6, lane = tid & 63;
  const int l15 = lane & 15, lg = lane >> 4;
  const long brow = (long)blockIdx.y * 128;
  const long bcol = (long)bx * 64;
  const int wr = (wave >> 1) * 64;    // 2x2 wave grid over 128x64
  const int wc = (wave & 1) * 32;

  f32x4 acc[4][2];
#pragma unroll
  for (int m = 0; m < 4; ++m)
#pragma unroll
    for (int n = 0; n < 2; ++n) acc[m][n] = (f32x4){0.f, 0.f, 0.f, 0.f};

  for (int kt = 0; kt < K; kt += 32) {
    // stage A: 8 segs x 1KB (128 rows x 64B)
#pragma unroll
    for (int j = 0; j < 2; ++j) {
      const int seg = wave * 2 + j;
      const int o = seg * 1024;
      const int ob = o + lane * 16;
      const int row = ob >> 6;
      const int cb = ob & 63;
      gload_lds16((const char*)A + ((brow + row) * (long)K + kt) * 2 + cb, (char*)As + o);
    }
    // stage B: 4 segs x 1KB (64 rows x 64B), waves 0-3 only
    if (wave < 4) {
      const int o = wave * 1024;
      const int ob = o + lane * 16;
      const int row = ob >> 6;
      const int cb = ob & 63;
      gload_lds16((const char*)Bt + ((bcol + row) * (long)K + kt) * 2 + cb, (char*)Bs + o);
    }
    __syncthreads();
    bf16x8 af[4], bfr[2];
#pragma unroll
    for (int m = 0; m < 4; ++m)
      af[m] = *(const bf16x8*)&As[(wr + m * 16 + l15) * 32 + lg * 8];
#pragma unroll
    for (int n = 0; n < 2; ++n)
      bfr[n] = *(const bf16x8*)&Bs[(wc + n * 16 + l15) * 32 + lg * 8];
#pragma unroll
    for (int m = 0; m < 4; ++m)
#pragma unroll
      for (int n = 0; n < 2; ++n)
        acc[m][n] = MFMA_BF16(af[m], bfr[n], acc[m][n]);
    __syncthreads();
  }

#pragma unroll
  for (int m = 0; m < 4; ++m)
#pragma unroll
    for (int n = 0; n < 2; ++n) {
      const long col = bcol + wc + n * 16 + l15;
      const float bv = bias[col];
      const long row0 = brow + wr + m * 16 + lg * 4;
      if (!sel) {
#pragma unroll
        for (int r = 0; r < 4; ++r)
          C0[(row0 + r) * N + col] = __float2bfloat16(acc[m][n][r] + bv);
      } else {
        const int bb = (int)(row0 >> 9);
        const int p = (int)(row0 & 511);
        ushort4 w;
        w.x = f2bu(acc[m][n][0] + bv);
        w.y = f2bu(acc[m][n][1] + bv);
        w.z = f2bu(acc[m][n][2] + bv);
        w.w = f2bu(acc[m][n][3] + bv);
        *(ushort4*)&Vt[((size_t)(bb * 1024 + col)) * 512 + p] = w;
      }
    }
}

// ---------------------------------------------------------------------------
// attention: grid (32 bh, 8), block 512 (8 waves), LDS 128KB (r14 base).
// Q PRESCALED by SC in the Q-GEMM -> P = exp2(s). Row-sum l via ones-MFMA
// (lac[0] = full row sum; MFMA K spans all lanes). First slice's Q frags
// loaded BEFORE __syncthreads so HBM fetch hides under K/V staging.
__global__ __launch_bounds__(512, 2) void attn_kernel(
    const __hip_bfloat16* __restrict__ Q,   // (B*S) x 1024, prescaled by SC
    const __hip_bfloat16* __restrict__ Km,  // (B*P) x 1024
    const __hip_bfloat16* __restrict__ Vt,  // (B*H*64) x 512 (= V^T panels)
    __hip_bfloat16* __restrict__ O) {       // (B*S) x 1024
  __shared__ alignas(16) __hip_bfloat16 Ks[512 * 64];   // [p][d], XOR-swizzled
  __shared__ alignas(16) __hip_bfloat16 VT[64 * 512];   // [d][p], XOR-swizzled
  const int bh = blockIdx.x;
  const int b = bh >> 4, h = bh & 15;
  const int tid = threadIdx.x, wave = tid >> 6, lane = tid & 63;
  const int l15 = lane & 15, lg = lane >> 4;
  const char* Kbase = (const char*)(Km + (size_t)b * 512 * 1024 + h * 64);
  const char* VtP = (const char*)(Vt + (size_t)bh * 32768);
  char* KsB = (char*)Ks;
  char* VTB = (char*)VT;

  // ---- stage K: linear LDS dest, XOR-pre-swizzled global source (m173)
#pragma unroll
  for (int j = 0; j < 8; ++j) {
    const int seg = wave * 8 + j;              // 64 segs x 8 rows x 128B
    const int p = seg * 8 + (lane >> 3);
    const int cb = ((lane & 7) * 16) ^ ((p & 7) << 4);
    gload_lds16(Kbase + (size_t)p * 2048 + cb, KsB + seg * 1024);
  }
  // ---- stage V^T rows (1024B each), source pre-swizzled (involution)
#pragma unroll
  for (int j = 0; j < 8; ++j) {
    const int d = wave * 8 + j;                // 0..63
    const int cb = (lane * 16) ^ ((d & 7) << 4);
    gload_lds16(VtP + (size_t)d * 1024 + cb, VTB + d * 1024);
  }

  const int y = blockIdx.y;
  // ---- preload Q for itq=0 (sidx = y) while staging is in flight
  int q0 = y * 256 + wave * 32;
  const __hip_bfloat16* Qr0 = Q + ((size_t)(b * 8192 + q0 + l15)) * 1024 + h * 64;
  const __hip_bfloat16* Qr1 = Qr0 + (size_t)16 * 1024;
  bf16x8 qa0 = *(const bf16x8*)(Qr0 + lg * 8);
  bf16x8 qa1 = *(const bf16x8*)(Qr0 + 32 + lg * 8);
  bf16x8 qb0 = *(const bf16x8*)(Qr1 + lg * 8);
  bf16x8 qb1 = *(const bf16x8*)(Qr1 + 32 + lg * 8);

  __syncthreads();

  const short one_bf = (short)0x3F80;          // 1.0 in bf16
  const bf16x8 ones = {one_bf, one_bf, one_bf, one_bf,
                       one_bf, one_bf, one_bf, one_bf};

  for (int itq = 0; itq < 4; ++itq) {
    // balanced slice map: block y gets {y, 15-y, 16+y, 31-y} -> 18 units each
    if (itq > 0) {
      const int sidx = (itq == 1) ? 15 - y : (itq == 2) ? 16 + y : 31 - y;
      q0 = sidx * 256 + wave * 32;
      const __hip_bfloat16* Qs0 = Q + ((size_t)(b * 8192 + q0 + l15)) * 1024 + h * 64;
      const __hip_bfloat16* Qs1 = Qs0 + (size_t)16 * 1024;
      qa0 = *(const bf16x8*)(Qs0 + lg * 8);
      qa1 = *(const bf16x8*)(Qs0 + 32 + lg * 8);
      qb0 = *(const bf16x8*)(Qs1 + lg * 8);
      qb1 = *(const bf16x8*)(Qs1 + 32 + lg * 8);
    }

    f32x4 lac0 = {0.f, 0.f, 0.f, 0.f}, lac1 = {0.f, 0.f, 0.f, 0.f};
    f32x4 o4[2][4];
#pragma unroll
    for (int g = 0; g < 2; ++g)
#pragma unroll
      for (int d = 0; d < 4; ++d) o4[g][d] = (f32x4){0.f, 0.f, 0.f, 0.f};

#pragma unroll
    for (int ch = 0; ch < 4; ++ch) {
      if (!(ch == 0 || q0 == 0 || q0 >= ch * 1024)) continue;

      // ---- scores^T: s[g][cc][r] = S[q0+g*16+l15][ch*128+cc*16+lg*4+r]
      f32x4 s[2][8];
#pragma unroll
      for (int cc = 0; cc < 8; ++cc) {
        const int p = ch * 128 + cc * 16 + l15;
        const int rb = p * 128;
        const int sw = (p & 7) << 4;
        const bf16x8 kf0 = *(const bf16x8*)(KsB + rb + ((lg * 16) ^ sw));
        const bf16x8 kf1 = *(const bf16x8*)(KsB + rb + ((lg * 16 + 64) ^ sw));
        f32x4 z0 = {0.f, 0.f, 0.f, 0.f};
        z0 = MFMA_BF16(kf0, qa0, z0);
        z0 = MFMA_BF16(kf1, qa1, z0);
        s[0][cc] = z0;
        f32x4 z1 = {0.f, 0.f, 0.f, 0.f};
        z1 = MFMA_BF16(kf0, qb0, z1);
        z1 = MFMA_BF16(kf1, qb1, z1);
        s[1][cc] = z1;
      }
      // ---- mask only on boundary chunks (wave-uniform test)
      if (q0 < (ch + 1) * 1024) {
#pragma unroll
        for (int g = 0; g < 2; ++g) {
          const int qa = q0 + g * 16 + l15;
          const float mval = (qa >= 8) ? -1.0e9f : 0.f;  // q<8: uniform row
#pragma unroll
          for (int cc = 0; cc < 8; ++cc) {
            const int pb8 = (ch * 128 + cc * 16 + lg * 4 + 1) * 8;
#pragma unroll
            for (int r = 0; r < 4; ++r)
              if (qa < pb8 + r * 8) s[g][cc][r] = mval;
          }
        }
      }
      // ---- fixed-base softmax: P = exp2(s) (Q prescaled)
#pragma unroll
      for (int cc = 0; cc < 8; ++cc)
#pragma unroll
        for (int r = 0; r < 4; ++r) {
          s[0][cc][r] = fexp2(s[0][cc][r]);
          s[1][cc][r] = fexp2(s[1][cc][r]);
        }
      // ---- PV + l-sum: B-frag via cvt_pk; l accumulated by ones-MFMA
#pragma unroll
      for (int kc = 0; kc < 4; ++kc) {
        uint4 u0, u1;
        u0.x = cvtpk(s[0][kc * 2][0], s[0][kc * 2][1]);
        u0.y = cvtpk(s[0][kc * 2][2], s[0][kc * 2][3]);
        u0.z = cvtpk(s[0][kc * 2 + 1][0], s[0][kc * 2 + 1][1]);
        u0.w = cvtpk(s[0][kc * 2 + 1][2], s[0][kc * 2 + 1][3]);
        u1.x = cvtpk(s[1][kc * 2][0], s[1][kc * 2][1]);
        u1.y = cvtpk(s[1][kc * 2][2], s[1][kc * 2][3]);
        u1.z = cvtpk(s[1][kc * 2 + 1][0], s[1][kc * 2 + 1][1]);
        u1.w = cvtpk(s[1][kc * 2 + 1][2], s[1][kc * 2 + 1][3]);
        const bf16x8 p0 = __builtin_bit_cast(bf16x8, u0);
        const bf16x8 p1 = __builtin_bit_cast(bf16x8, u1);
        lac0 = MFMA_BF16(ones, p0, lac0);
        lac1 = MFMA_BF16(ones, p1, lac1);
        const int pbase = ch * 128 + kc * 32;
#pragma unroll
        for (int db = 0; db < 4; ++db) {
          const int d = db * 16 + l15;
          const int rowb = d * 1024;
          const int sw = (d & 7) << 4;
          const bf16x4 v0 = *(const bf16x4*)(VTB + rowb + (((pbase + lg * 4) * 2) ^ sw));
          const bf16x4 v1 = *(const bf16x4*)(VTB + rowb + (((pbase + 16 + lg * 4) * 2) ^ sw));
          const bf16x8 af = {v0[0], v0[1], v0[2], v0[3], v1[0], v1[1], v1[2], v1[3]};
          o4[0][db] = MFMA_BF16(af, p0, o4[0][db]);
          o4[1][db] = MFMA_BF16(af, p1, o4[1][db]);
        }
      }
    }
    // ---- normalize: lac[0] is the FULL row sum; store via cvt_pk
#pragma unroll
    for (int g = 0; g < 2; ++g) {
      const float inv = 1.f / (g ? lac1[0] : lac0[0]);
      __hip_bfloat16* Op =
          O + ((size_t)(b * 8192 + q0 + g * 16 + l15)) * 1024 + h * 64 + lg * 4;
#pragma unroll
      for (int db = 0; db < 4; ++db) {
        uint2 w;
        w.x = cvtpk(o4[g][db][0] * inv, o4[g][db][1] * inv);
        w.y = cvtpk(o4[g][db][2] * inv, o4[g][db][3] * inv);
        *(uint2*)(Op + db * 16) = w;
      }
    }
  }
}

// ---------------------------------------------------------------------------
extern "C" void kernel_launch(void* const* d_in, const int* in_sizes, int n_in,
                              void* d_out, int out_size, void* d_ws, size_t ws_size,
                              hipStream_t stream) {
  const float* x  = (const float*)d_in[0];
  const float* Wq = (const float*)d_in[2];
  const float* bq = (const float*)d_in[3];
  const float* Wk = (const float*)d_in[4];
  const float* bk = (const float*)d_in[5];
  const float* Wv = (const float*)d_in[6];
  const float* bv = (const float*)d_in[7];
  const float* Wo = (const float*)d_in[8];
  const float* bo = (const float*)d_in[9];
  float* out = (float*)d_out;

  constexpr size_t SZ_XB = (size_t)16384 * 1024 * 2;  // 32 MB
  constexpr size_t SZ_WT = (size_t)1024 * 1024 * 2;   // 2 MB
  constexpr size_t SZ_CB = (size_t)1024 * 1024 * 2;   // 2 MB
  char* ws = (char*)d_ws;
  __hip_bfloat16* xb   = (__hip_bfloat16*)ws;                                   // also attn_out
  __hip_bfloat16* WqT  = (__hip_bfloat16*)(ws + SZ_XB);
  __hip_bfloat16* WkT  = (__hip_bfloat16*)(ws + SZ_XB + SZ_WT);
  __hip_bfloat16* WvT  = (__hip_bfloat16*)(ws + SZ_XB + 2 * SZ_WT);
  __hip_bfloat16* WoT  = (__hip_bfloat16*)(ws + SZ_XB + 3 * SZ_WT);
  __hip_bfloat16* cbuf = (__hip_bfloat16*)(ws + SZ_XB + 4 * SZ_WT);
  __hip_bfloat16* Qb   = (__hip_bfloat16*)(ws + SZ_XB + 4 * SZ_WT + SZ_CB);
  __hip_bfloat16* Kb   = (__hip_bfloat16*)(ws + SZ_XB + 4 * SZ_WT + SZ_CB + SZ_XB);
  __hip_bfloat16* Vtb  = (__hip_bfloat16*)(ws + SZ_XB + 4 * SZ_WT + SZ_CB + SZ_XB + SZ_CB);

  constexpr float SC = 0.18033688011112042f;  // 0.125 * log2(e)

  prep_kernel<<<dim3(6144), dim3(256), 0, stream>>>(
      x, xb, cbuf, Wq, Wk, Wv, Wo, WqT, WkT, WvT, WoT);
  gemm256_kernel<__hip_bfloat16><<<dim3(256), dim3(512), 0, stream>>>(
      xb, WqT, bq, Qb, 16384, 1024, 1024, SC);
  gemm_bt_dual_kernel<<<dim3(32, 8), dim3(256), 0, stream>>>(
      cbuf, WkT, bk, Kb, WvT, bv, Vtb, 1024, 1024, 1024);
  attn_kernel<<<dim3(32, 8), dim3(512), 0, stream>>>(Qb, Kb, Vtb, xb);
  gemm256_kernel<float><<<dim3(256), dim3(512), 0, stream>>>(
      xb, WoT, bo, out, 16384, 1024, 1024, 1.0f);
}

// Round 16
// 156.304 us; speedup vs baseline: 1.1197x; 1.1197x over previous
//
#include <hip/hip_runtime.h>
#include <hip/hip_bf16.h>

// ---------------------------------------------------------------------------
// CompressedGlobalAttention: B=2, S=8192, D=1024, H=16, Hd=64, R=8,
// local_window_start=4096 -> P=512 pools.
//   1. prep kernel: fused {cast+compress} and {weight transpose}
//   2. Q via 8-phase 256^2 GEMM with epilogue PRESCALE by 0.125*log2(e);
//      K/V via fused dual GEMM retiled 128x64 (grid 256 = all CUs)
//   3. attention per (b,h): r14 structure EXACTLY (Q loads inside itq loop,
//      after barrier - r15's hoist of Q across the staging barrier pushed
//      liveness past the 128-VGPR quantum -> spill, +11us). Fixed-base
//      softmax P = exp2(s) (Q prescaled), l via ones-MFMA (lac[0] = full
//      row sum).
//   4. out via 8-phase 256^2 GEMM (oscale=1, f32 out)
// Dead-ends (measured): 1024-thr blocks (64-VGPR cliff r2/r8), (512,1)
// doesn't lift 128 cap (r12), global-K (r5), global-V (r6), LDS-halving
// (r9), 4-q-group widening (r12), cvt_pk alone (r10), balance/setprio
// (r11), Q-preload hoist (r15 spill).
// ---------------------------------------------------------------------------

typedef __attribute__((ext_vector_type(8))) short bf16x8;
typedef __attribute__((ext_vector_type(4))) short bf16x4;
typedef __attribute__((ext_vector_type(4))) float f32x4;

#define MFMA_BF16(a, b, c) __builtin_amdgcn_mfma_f32_16x16x32_bf16((a), (b), (c), 0, 0, 0)

__device__ __forceinline__ unsigned short f2bu(float x) {
  __hip_bfloat16 b = __float2bfloat16(x);
  return __builtin_bit_cast(unsigned short, b);
}

__device__ __forceinline__ unsigned cvtpk(float lo, float hi) {
  unsigned r;
  asm("v_cvt_pk_bf16_f32 %0, %1, %2" : "=v"(r) : "v"(lo), "v"(hi));
  return r;
}

__device__ __forceinline__ float fexp2(float x) {
  float r;
  asm("v_exp_f32 %0, %1" : "=v"(r) : "v"(x));
  return r;
}

__device__ __forceinline__ void gload_lds16(const void* g, void* l) {
  __builtin_amdgcn_global_load_lds(
      (const __attribute__((address_space(1))) unsigned*)(g),
      (__attribute__((address_space(3))) unsigned*)(l), 16, 0, 0);
}

__device__ __forceinline__ unsigned ldsaddr(const void* p) {
  return (unsigned)(unsigned long long)(const __attribute__((address_space(3))) char*)p;
}

// ---------------------------------------------------------------------------
// prep: blocks [0,2048) = cast x->bf16 + avg-pool compress;
//       blocks [2048,6144) = transpose 1024x1024 f32 weight -> bf16 Bt
__global__ void prep_kernel(const float* __restrict__ x,
                            __hip_bfloat16* __restrict__ xb,
                            __hip_bfloat16* __restrict__ cb,
                            const float* __restrict__ w0, const float* __restrict__ w1,
                            const float* __restrict__ w2, const float* __restrict__ w3,
                            __hip_bfloat16* __restrict__ t0, __hip_bfloat16* __restrict__ t1,
                            __hip_bfloat16* __restrict__ t2, __hip_bfloat16* __restrict__ t3) {
  __shared__ float tile[32][33];
  const int bid = blockIdx.x;
  const int tid = threadIdx.x;
  if (bid < 2048) {
    const int b = bid >> 10, g = bid & 1023;
    const int d = tid * 4;
    const size_t rb = ((size_t)(b * 8192 + g * 8)) * 1024 + d;
    float4 a = {0.f, 0.f, 0.f, 0.f};
#pragma unroll
    for (int r = 0; r < 8; ++r) {
      const float4 v = *(const float4*)&x[rb + (size_t)r * 1024];
      ushort4 o;
      o.x = f2bu(v.x); o.y = f2bu(v.y); o.z = f2bu(v.z); o.w = f2bu(v.w);
      *(ushort4*)&xb[rb + (size_t)r * 1024] = o;
      a.x += v.x; a.y += v.y; a.z += v.z; a.w += v.w;
    }
    if (g < 512) {
      ushort4 o;
      o.x = f2bu(a.x * 0.125f); o.y = f2bu(a.y * 0.125f);
      o.z = f2bu(a.z * 0.125f); o.w = f2bu(a.w * 0.125f);
      *(ushort4*)&cb[((size_t)(b * 512 + g)) * 1024 + d] = o;
    }
  } else {
    const int t = bid - 2048;
    const int z = t >> 10, rem = t & 1023;
    const int k0 = (rem & 31) * 32, n0 = (rem >> 5) * 32;
    const float* W; __hip_bfloat16* T;
    switch (z) {
      case 0: W = w0; T = t0; break;
      case 1: W = w1; T = t1; break;
      case 2: W = w2; T = t2; break;
      default: W = w3; T = t3; break;
    }
    const int tx = tid & 31, ty = tid >> 5;          // 32 x 8
#pragma unroll
    for (int j = 0; j < 4; ++j) {
      const int kk = ty + j * 8;
      tile[kk][tx] = W[(size_t)(k0 + kk) * 1024 + n0 + tx];
    }
    __syncthreads();
#pragma unroll
    for (int j = 0; j < 4; ++j) {
      const int nn = ty + j * 8;
      T[(size_t)(n0 + nn) * 1024 + k0 + tx] = __float2bfloat16(tile[tx][nn]);
    }
  }
}

// ---------------------------------------------------------------------------
// 8-phase 256x256xBK=64 GEMM (T2 swizzle + T3/T4 counted vmcnt + T5 setprio).
// Epilogue: C = (acc + bias) * oscale.
// ---------------------------------------------------------------------------

#define STAGE(SPTR, SROWBASE, STILE, SLDSOFF)                                  \
  {                                                                            \
    const int _t = (STILE) < NT ? (STILE) : 0;                                 \
    const size_t _kb = (size_t)_t * 128;                                       \
    gload_lds16((const char*)(SPTR) + ((size_t)((SROWBASE) + srow0) * K) * 2 + _kb + scb0, \
                ldsC + (SLDSOFF) + wave * 1024);                               \
    gload_lds16((const char*)(SPTR) + ((size_t)((SROWBASE) + srow0 + 64) * K) * 2 + _kb + scb0, \
                ldsC + (SLDSOFF) + 8192 + wave * 1024);                        \
  }

#define MM4(MR, AF0, AF1)                                                      \
  acc[MR][0] = MFMA_BF16(AF0, bf00, acc[MR][0]);                               \
  acc[MR][1] = MFMA_BF16(AF0, bf10, acc[MR][1]);                               \
  acc[MR][2] = MFMA_BF16(AF0, bf20, acc[MR][2]);                               \
  acc[MR][3] = MFMA_BF16(AF0, bf30, acc[MR][3]);                               \
  acc[MR][0] = MFMA_BF16(AF1, bf01, acc[MR][0]);                               \
  acc[MR][1] = MFMA_BF16(AF1, bf11, acc[MR][1]);                               \
  acc[MR][2] = MFMA_BF16(AF1, bf21, acc[MR][2]);                               \
  acc[MR][3] = MFMA_BF16(AF1, bf31, acc[MR][3]);

#define PHASE(QM, DB, LOADB, SPTR, SROWBASE, STILE, SLDSOFF, DOVM)             \
  {                                                                            \
    bf16x8 af0, af1, af2, af3;                                                 \
    const unsigned ab = Ab0 + (DB)*32768u + (QM)*4096u;                        \
    asm volatile("ds_read_b128 %0, %1" : "=v"(af0) : "v"(ab));                 \
    asm volatile("ds_read_b128 %0, %1" : "=v"(af1) : "v"(ab ^ 64u));           \
    asm volatile("ds_read_b128 %0, %1" : "=v"(af2) : "v"(ab + 2048u));         \
    asm volatile("ds_read_b128 %0, %1" : "=v"(af3) : "v"((ab + 2048u) ^ 64u)); \
    if (LOADB) {                                                               \
      const unsigned bb = Bb0 + (DB)*32768u;                                   \
      asm volatile("ds_read_b128 %0, %1" : "=v"(bf00) : "v"(bb));              \
      asm volatile("ds_read_b128 %0, %1" : "=v"(bf01) : "v"(bb ^ 64u));        \
      asm volatile("ds_read_b128 %0, %1" : "=v"(bf10) : "v"(bb + 2048u));      \
      asm volatile("ds_read_b128 %0, %1" : "=v"(bf11) : "v"((bb + 2048u) ^ 64u)); \
      asm volatile("ds_read_b128 %0, %1" : "=v"(bf20) : "v"(bb + 4096u));      \
      asm volatile("ds_read_b128 %0, %1" : "=v"(bf21) : "v"((bb + 4096u) ^ 64u)); \
      asm volatile("ds_read_b128 %0, %1" : "=v"(bf30) : "v"(bb + 6144u));      \
      asm volatile("ds_read_b128 %0, %1" : "=v"(bf31) : "v"((bb + 6144u) ^ 64u)); \
    }                                                                          \
    STAGE(SPTR, SROWBASE, STILE, SLDSOFF)                                      \
    asm volatile("s_barrier" ::: "memory");                                    \
    asm volatile("s_waitcnt lgkmcnt(0)" ::: "memory");                         \
    __builtin_amdgcn_sched_barrier(0);                                         \
    __builtin_amdgcn_s_setprio(1);                                             \
    MM4((QM)*2 + 0, af0, af1)                                                  \
    MM4((QM)*2 + 1, af2, af3)                                                  \
    __builtin_amdgcn_s_setprio(0);                                             \
    if (DOVM) asm volatile("s_waitcnt vmcnt(4)" ::: "memory");                 \
    asm volatile("s_barrier" ::: "memory");                                    \
  }

template <typename OUT_T>
__global__ __launch_bounds__(512, 2) void gemm256_kernel(
    const __hip_bfloat16* __restrict__ A, const __hip_bfloat16* __restrict__ Bt,
    const float* __restrict__ bias, OUT_T* __restrict__ C, int M, int N, int K,
    float oscale) {
  __shared__ alignas(16) char lds[131072];
  char* ldsC = lds;
  const int tid = threadIdx.x;
  const int wave = tid >> 6, lane = tid & 63;
  const int l15 = lane & 15, lg = lane >> 4;
  const int wm = wave >> 2, wn = wave & 3;

  const int nwg = gridDim.x, cpx = nwg >> 3;
  const int bid = blockIdx.x;
  const int swz = (bid & 7) * cpx + (bid >> 3);
  const int ncol = N >> 8;
  const int bn = swz % ncol, bm = swz / ncol;
  const long brow = (long)bm * 256;
  const long bcol = (long)bn * 256;

  const int NT = K >> 6;
  const int NITER = K >> 7;

  const int o0 = wave * 1024 + lane * 16;
  const int srow0 = o0 >> 7;
  const int scb0 = (o0 & 127) ^ ((srow0 & 7) << 4);

  const unsigned LB = ldsaddr(lds);
  const int off0 = (lg * 16) ^ ((l15 & 7) << 4);
  const unsigned Ab0 = LB + wm * 16384u + l15 * 128u + off0;
  const unsigned Bb0 = LB + 65536u + (wn >> 1) * 16384u + (wn & 1) * 8192u + l15 * 128u + off0;

  f32x4 acc[8][4];
#pragma unroll
  for (int m = 0; m < 8; ++m)
#pragma unroll
    for (int n = 0; n < 4; ++n) acc[m][n] = (f32x4){0.f, 0.f, 0.f, 0.f};

  bf16x8 bf00, bf01, bf10, bf11, bf20, bf21, bf30, bf31;

  STAGE(Bt, bcol + 128, 0, 81920)
  STAGE(Bt, bcol,       0, 65536)
  STAGE(A,  brow,       0, 0)
  STAGE(A,  brow + 128, 0, 16384)
  STAGE(Bt, bcol + 128, 1, 114688)
  STAGE(Bt, bcol,       1, 98304)
  asm volatile("s_waitcnt vmcnt(4)" ::: "memory");
  asm volatile("s_barrier" ::: "memory");

  for (int i = 0; i < NITER; ++i) {
    const int t0 = 2 * i;
    PHASE(0, 0, true,  A,  brow,       t0 + 1, 32768,  false)
    PHASE(1, 0, false, A,  brow + 128, t0 + 1, 49152,  false)
    PHASE(2, 0, false, Bt, bcol + 128, t0 + 2, 81920,  false)
    PHASE(3, 0, false, Bt, bcol,       t0 + 2, 65536,  true)
    PHASE(0, 1, true,  A,  brow,       t0 + 2, 0,      false)
    PHASE(1, 1, false, A,  brow + 128, t0 + 2, 16384,  false)
    PHASE(2, 1, false, Bt, bcol + 128, t0 + 3, 114688, false)
    PHASE(3, 1, false, Bt, bcol,       t0 + 3, 98304,  true)
  }

#pragma unroll
  for (int nn = 0; nn < 4; ++nn) {
    const long col = bcol + wn * 64 + nn * 16 + l15;
    const float bv = bias[col];
#pragma unroll
    for (int mr = 0; mr < 8; ++mr) {
      const long row = brow + wm * 128 + mr * 16 + lg * 4;
#pragma unroll
      for (int j = 0; j < 4; ++j) {
        const float v = (acc[mr][nn][j] + bv) * oscale;
        if constexpr (sizeof(OUT_T) == 2)
          C[(row + j) * N + col] = __float2bfloat16(v);
        else
          C[(row + j) * N + col] = v;
      }
    }
  }
}

// ---------------------------------------------------------------------------
// dual K/V projection GEMM, retiled 128x64 so grid = 256 (all CUs busy).
// grid (32, 8): x<16 -> K-proj col-tile x; x>=16 -> V-proj col-tile x-16.
// K written normally; V written TRANSPOSED: Vt[(b*1024 + h*64 + d)*512 + p]
__global__ __launch_bounds__(256, 2) void gemm_bt_dual_kernel(
    const __hip_bfloat16* __restrict__ A,
    const __hip_bfloat16* __restrict__ Bt0, const float* __restrict__ b0,
    __hip_bfloat16* __restrict__ C0,
    const __hip_bfloat16* __restrict__ Bt1, const float* __restrict__ b1,
    __hip_bfloat16* __restrict__ Vt, int M, int N, int K) {
  const int sel = blockIdx.x >= 16;
  const __hip_bfloat16* Bt = sel ? Bt1 : Bt0;
  const float* bias = sel ? b1 : b0;
  const int bx = blockIdx.x - (sel ? 16 : 0);

  __shared__ alignas(16) __hip_bfloat16 As[128 * 32];
  __shared__ alignas(16) __hip_bfloat16 Bs[64 * 32];
  const int tid = threadIdx.x;
  const int wave = tid >> 6, lane = tid & 63;
  const int l15 = lane & 15, lg = lane >> 4;
  const long brow = (long)blockIdx.y * 128;
  const long bcol = (long)bx * 64;
  const int wr = (wave >> 1) * 64;    // 2x2 wave grid over 128x64
  const int wc = (wave & 1) * 32;

  f32x4 acc[4][2];
#pragma unroll
  for (int m = 0; m < 4; ++m)
#pragma unroll
    for (int n = 0; n < 2; ++n) acc[m][n] = (f32x4){0.f, 0.f, 0.f, 0.f};

  for (int kt = 0; kt < K; kt += 32) {
#pragma unroll
    for (int j = 0; j < 2; ++j) {
      const int seg = wave * 2 + j;
      const int o = seg * 1024;
      const int ob = o + lane * 16;
      const int row = ob >> 6;
      const int cb = ob & 63;
      gload_lds16((const char*)A + ((brow + row) * (long)K + kt) * 2 + cb, (char*)As + o);
    }
    if (wave < 4) {
      const int o = wave * 1024;
      const int ob = o + lane * 16;
      const int row = ob >> 6;
      const int cb = ob & 63;
      gload_lds16((const char*)Bt + ((bcol + row) * (long)K + kt) * 2 + cb, (char*)Bs + o);
    }
    __syncthreads();
    bf16x8 af[4], bfr[2];
#pragma unroll
    for (int m = 0; m < 4; ++m)
      af[m] = *(const bf16x8*)&As[(wr + m * 16 + l15) * 32 + lg * 8];
#pragma unroll
    for (int n = 0; n < 2; ++n)
      bfr[n] = *(const bf16x8*)&Bs[(wc + n * 16 + l15) * 32 + lg * 8];
#pragma unroll
    for (int m = 0; m < 4; ++m)
#pragma unroll
      for (int n = 0; n < 2; ++n)
        acc[m][n] = MFMA_BF16(af[m], bfr[n], acc[m][n]);
    __syncthreads();
  }

#pragma unroll
  for (int m = 0; m < 4; ++m)
#pragma unroll
    for (int n = 0; n < 2; ++n) {
      const long col = bcol + wc + n * 16 + l15;
      const float bv = bias[col];
      const long row0 = brow + wr + m * 16 + lg * 4;
      if (!sel) {
#pragma unroll
        for (int r = 0; r < 4; ++r)
          C0[(row0 + r) * N + col] = __float2bfloat16(acc[m][n][r] + bv);
      } else {
        const int bb = (int)(row0 >> 9);
        const int p = (int)(row0 & 511);
        ushort4 w;
        w.x = f2bu(acc[m][n][0] + bv);
        w.y = f2bu(acc[m][n][1] + bv);
        w.z = f2bu(acc[m][n][2] + bv);
        w.w = f2bu(acc[m][n][3] + bv);
        *(ushort4*)&Vt[((size_t)(bb * 1024 + col)) * 512 + p] = w;
      }
    }
}

// ---------------------------------------------------------------------------
// attention: grid (32 bh, 8), block 512 (8 waves), LDS 128KB -- r14 kernel
// EXACTLY (proven 128-VGPR, no spill, ~42us). Q PRESCALED by SC in Q-GEMM;
// P = exp2(s); l via ones-MFMA (lac[0] = full row sum, no cross-lane reduce).
__global__ __launch_bounds__(512, 2) void attn_kernel(
    const __hip_bfloat16* __restrict__ Q,   // (B*S) x 1024, prescaled by SC
    const __hip_bfloat16* __restrict__ Km,  // (B*P) x 1024
    const __hip_bfloat16* __restrict__ Vt,  // (B*H*64) x 512 (= V^T panels)
    __hip_bfloat16* __restrict__ O) {       // (B*S) x 1024
  __shared__ alignas(16) __hip_bfloat16 Ks[512 * 64];   // [p][d], XOR-swizzled
  __shared__ alignas(16) __hip_bfloat16 VT[64 * 512];   // [d][p], XOR-swizzled
  const int bh = blockIdx.x;
  const int b = bh >> 4, h = bh & 15;
  const int tid = threadIdx.x, wave = tid >> 6, lane = tid & 63;
  const int l15 = lane & 15, lg = lane >> 4;
  const char* Kbase = (const char*)(Km + (size_t)b * 512 * 1024 + h * 64);
  const char* VtP = (const char*)(Vt + (size_t)bh * 32768);
  char* KsB = (char*)Ks;
  char* VTB = (char*)VT;

  // ---- stage K: linear LDS dest, XOR-pre-swizzled global source (m173)
#pragma unroll
  for (int j = 0; j < 8; ++j) {
    const int seg = wave * 8 + j;              // 64 segs x 8 rows x 128B
    const int p = seg * 8 + (lane >> 3);
    const int cb = ((lane & 7) * 16) ^ ((p & 7) << 4);
    gload_lds16(Kbase + (size_t)p * 2048 + cb, KsB + seg * 1024);
  }
  // ---- stage V^T rows (1024B each), source pre-swizzled (involution)
#pragma unroll
  for (int j = 0; j < 8; ++j) {
    const int d = wave * 8 + j;                // 0..63
    const int cb = (lane * 16) ^ ((d & 7) << 4);
    gload_lds16(VtP + (size_t)d * 1024 + cb, VTB + d * 1024);
  }
  __syncthreads();

  const short one_bf = (short)0x3F80;          // 1.0 in bf16
  const bf16x8 ones = {one_bf, one_bf, one_bf, one_bf,
                       one_bf, one_bf, one_bf, one_bf};

  for (int itq = 0; itq < 4; ++itq) {
    // balanced slice map: block y gets {y, 15-y, 16+y, 31-y} -> 18 units each
    const int y = blockIdx.y;
    const int sidx = (itq == 0) ? y : (itq == 1) ? 15 - y
                   : (itq == 2) ? 16 + y : 31 - y;
    const int q0 = sidx * 256 + wave * 32;
    const __hip_bfloat16* Qr0 = Q + ((size_t)(b * 8192 + q0 + l15)) * 1024 + h * 64;
    const __hip_bfloat16* Qr1 = Qr0 + (size_t)16 * 1024;
    const bf16x8 qa0 = *(const bf16x8*)(Qr0 + lg * 8);
    const bf16x8 qa1 = *(const bf16x8*)(Qr0 + 32 + lg * 8);
    const bf16x8 qb0 = *(const bf16x8*)(Qr1 + lg * 8);
    const bf16x8 qb1 = *(const bf16x8*)(Qr1 + 32 + lg * 8);

    f32x4 lac0 = {0.f, 0.f, 0.f, 0.f}, lac1 = {0.f, 0.f, 0.f, 0.f};
    f32x4 o4[2][4];
#pragma unroll
    for (int g = 0; g < 2; ++g)
#pragma unroll
      for (int d = 0; d < 4; ++d) o4[g][d] = (f32x4){0.f, 0.f, 0.f, 0.f};

#pragma unroll
    for (int ch = 0; ch < 4; ++ch) {
      if (!(ch == 0 || q0 == 0 || q0 >= ch * 1024)) continue;

      // ---- scores^T: s[g][cc][r] = S[q0+g*16+l15][ch*128+cc*16+lg*4+r]
      f32x4 s[2][8];
#pragma unroll
      for (int cc = 0; cc < 8; ++cc) {
        const int p = ch * 128 + cc * 16 + l15;
        const int rb = p * 128;
        const int sw = (p & 7) << 4;
        const bf16x8 kf0 = *(const bf16x8*)(KsB + rb + ((lg * 16) ^ sw));
        const bf16x8 kf1 = *(const bf16x8*)(KsB + rb + ((lg * 16 + 64) ^ sw));
        f32x4 z0 = {0.f, 0.f, 0.f, 0.f};
        z0 = MFMA_BF16(kf0, qa0, z0);
        z0 = MFMA_BF16(kf1, qa1, z0);
        s[0][cc] = z0;
        f32x4 z1 = {0.f, 0.f, 0.f, 0.f};
        z1 = MFMA_BF16(kf0, qb0, z1);
        z1 = MFMA_BF16(kf1, qb1, z1);
        s[1][cc] = z1;
      }
      // ---- mask only on boundary chunks (wave-uniform test)
      if (q0 < (ch + 1) * 1024) {
#pragma unroll
        for (int g = 0; g < 2; ++g) {
          const int qa = q0 + g * 16 + l15;
          const float mval = (qa >= 8) ? -1.0e9f : 0.f;  // q<8: uniform row
#pragma unroll
          for (int cc = 0; cc < 8; ++cc) {
            const int pb8 = (ch * 128 + cc * 16 + lg * 4 + 1) * 8;
#pragma unroll
            for (int r = 0; r < 4; ++r)
              if (qa < pb8 + r * 8) s[g][cc][r] = mval;
          }
        }
      }
      // ---- fixed-base softmax: P = exp2(s) (Q prescaled)
#pragma unroll
      for (int cc = 0; cc < 8; ++cc)
#pragma unroll
        for (int r = 0; r < 4; ++r) {
          s[0][cc][r] = fexp2(s[0][cc][r]);
          s[1][cc][r] = fexp2(s[1][cc][r]);
        }
      // ---- PV + l-sum: B-frag via cvt_pk; l accumulated by ones-MFMA
#pragma unroll
      for (int kc = 0; kc < 4; ++kc) {
        uint4 u0, u1;
        u0.x = cvtpk(s[0][kc * 2][0], s[0][kc * 2][1]);
        u0.y = cvtpk(s[0][kc * 2][2], s[0][kc * 2][3]);
        u0.z = cvtpk(s[0][kc * 2 + 1][0], s[0][kc * 2 + 1][1]);
        u0.w = cvtpk(s[0][kc * 2 + 1][2], s[0][kc * 2 + 1][3]);
        u1.x = cvtpk(s[1][kc * 2][0], s[1][kc * 2][1]);
        u1.y = cvtpk(s[1][kc * 2][2], s[1][kc * 2][3]);
        u1.z = cvtpk(s[1][kc * 2 + 1][0], s[1][kc * 2 + 1][1]);
        u1.w = cvtpk(s[1][kc * 2 + 1][2], s[1][kc * 2 + 1][3]);
        const bf16x8 p0 = __builtin_bit_cast(bf16x8, u0);
        const bf16x8 p1 = __builtin_bit_cast(bf16x8, u1);
        lac0 = MFMA_BF16(ones, p0, lac0);
        lac1 = MFMA_BF16(ones, p1, lac1);
        const int pbase = ch * 128 + kc * 32;
#pragma unroll
        for (int db = 0; db < 4; ++db) {
          const int d = db * 16 + l15;
          const int rowb = d * 1024;
          const int sw = (d & 7) << 4;
          const bf16x4 v0 = *(const bf16x4*)(VTB + rowb + (((pbase + lg * 4) * 2) ^ sw));
          const bf16x4 v1 = *(const bf16x4*)(VTB + rowb + (((pbase + 16 + lg * 4) * 2) ^ sw));
          const bf16x8 af = {v0[0], v0[1], v0[2], v0[3], v1[0], v1[1], v1[2], v1[3]};
          o4[0][db] = MFMA_BF16(af, p0, o4[0][db]);
          o4[1][db] = MFMA_BF16(af, p1, o4[1][db]);
        }
      }
    }
    // ---- normalize: lac[0] is the FULL row sum; store via cvt_pk
#pragma unroll
    for (int g = 0; g < 2; ++g) {
      const float inv = 1.f / (g ? lac1[0] : lac0[0]);
      __hip_bfloat16* Op =
          O + ((size_t)(b * 8192 + q0 + g * 16 + l15)) * 1024 + h * 64 + lg * 4;
#pragma unroll
      for (int db = 0; db < 4; ++db) {
        uint2 w;
        w.x = cvtpk(o4[g][db][0] * inv, o4[g][db][1] * inv);
        w.y = cvtpk(o4[g][db][2] * inv, o4[g][db][3] * inv);
        *(uint2*)(Op + db * 16) = w;
      }
    }
  }
}

// ---------------------------------------------------------------------------
extern "C" void kernel_launch(void* const* d_in, const int* in_sizes, int n_in,
                              void* d_out, int out_size, void* d_ws, size_t ws_size,
                              hipStream_t stream) {
  const float* x  = (const float*)d_in[0];
  const float* Wq = (const float*)d_in[2];
  const float* bq = (const float*)d_in[3];
  const float* Wk = (const float*)d_in[4];
  const float* bk = (const float*)d_in[5];
  const float* Wv = (const float*)d_in[6];
  const float* bv = (const float*)d_in[7];
  const float* Wo = (const float*)d_in[8];
  const float* bo = (const float*)d_in[9];
  float* out = (float*)d_out;

  constexpr size_t SZ_XB = (size_t)16384 * 1024 * 2;  // 32 MB
  constexpr size_t SZ_WT = (size_t)1024 * 1024 * 2;   // 2 MB
  constexpr size_t SZ_CB = (size_t)1024 * 1024 * 2;   // 2 MB
  char* ws = (char*)d_ws;
  __hip_bfloat16* xb   = (__hip_bfloat16*)ws;                                   // also attn_out
  __hip_bfloat16* WqT  = (__hip_bfloat16*)(ws + SZ_XB);
  __hip_bfloat16* WkT  = (__hip_bfloat16*)(ws + SZ_XB + SZ_WT);
  __hip_bfloat16* WvT  = (__hip_bfloat16*)(ws + SZ_XB + 2 * SZ_WT);
  __hip_bfloat16* WoT  = (__hip_bfloat16*)(ws + SZ_XB + 3 * SZ_WT);
  __hip_bfloat16* cbuf = (__hip_bfloat16*)(ws + SZ_XB + 4 * SZ_WT);
  __hip_bfloat16* Qb   = (__hip_bfloat16*)(ws + SZ_XB + 4 * SZ_WT + SZ_CB);
  __hip_bfloat16* Kb   = (__hip_bfloat16*)(ws + SZ_XB + 4 * SZ_WT + SZ_CB + SZ_XB);
  __hip_bfloat16* Vtb  = (__hip_bfloat16*)(ws + SZ_XB + 4 * SZ_WT + SZ_CB + SZ_XB + SZ_CB);

  constexpr float SC = 0.18033688011112042f;  // 0.125 * log2(e)

  prep_kernel<<<dim3(6144), dim3(256), 0, stream>>>(
      x, xb, cbuf, Wq, Wk, Wv, Wo, WqT, WkT, WvT, WoT);
  gemm256_kernel<__hip_bfloat16><<<dim3(256), dim3(512), 0, stream>>>(
      xb, WqT, bq, Qb, 16384, 1024, 1024, SC);
  gemm_bt_dual_kernel<<<dim3(32, 8), dim3(256), 0, stream>>>(
      cbuf, WkT, bk, Kb, WvT, bv, Vtb, 1024, 1024, 1024);
  attn_kernel<<<dim3(32, 8), dim3(512), 0, stream>>>(Qb, Kb, Vtb, xb);
  gemm256_kernel<float><<<dim3(256), dim3(512), 0, stream>>>(
      xb, WoT, bo, out, 16384, 1024, 1024, 1.0f);
}